// Round 7
// baseline (45218.704 us; speedup 1.0000x reference)
//
#include <hip/hip_runtime.h>
#include <hip/hip_bf16.h>
#include <cstdint>

#define B_ 256
#define D_ 128
#define T_ 512
#define H_ 256
#define C_ 10

using f32x4 = __attribute__((ext_vector_type(4))) float;
using s16x8 = __attribute__((ext_vector_type(8))) short;
using u32x4 = __attribute__((ext_vector_type(4))) unsigned int;

__device__ __forceinline__ unsigned short f2bf(float f) {
    union { float f; uint32_t u; } a; a.f = f;
    uint32_t u = a.u;
    uint32_t r = (u + 0x7fffu + ((u >> 16) & 1u)) >> 16;   // RNE
    return (unsigned short)r;
}

__device__ __forceinline__ float sigm(float v) { return 1.0f / (1.0f + __expf(-v)); }

__device__ __forceinline__ s16x8 as_frag(uint4 v) {
    union { uint4 u; s16x8 s; } c; c.u = v; return c.s;
}

// lgkm-only barrier: orders LDS without draining in-flight global ops.
__device__ __forceinline__ void bar_lds() {
    asm volatile("s_waitcnt lgkmcnt(0)\n\ts_barrier" ::: "memory");
}

// sc0 loads: bypass L1, served by this XCD's L2 (the shared coherence point
// for same-XCD blocks). NOT coherent cross-XCD — gated by the runtime probe.
__device__ __forceinline__ int load_i32_sc0(const int* p) {
    int v;
    asm volatile("global_load_dword %0, %1, off sc0\n\ts_waitcnt vmcnt(0)"
                 : "=&v"(v) : "v"(p) : "memory");
    return v;
}
__device__ __forceinline__ void load_64B_sc0(const uint64_t* p,
                                             u32x4& q0, u32x4& q1, u32x4& q2, u32x4& q3) {
    asm volatile("global_load_dwordx4 %0, %4, off sc0\n\t"
                 "global_load_dwordx4 %1, %4, off offset:16 sc0\n\t"
                 "global_load_dwordx4 %2, %4, off offset:32 sc0\n\t"
                 "global_load_dwordx4 %3, %4, off offset:48 sc0\n\t"
                 "s_waitcnt vmcnt(0)"
                 : "=&v"(q0), "=&v"(q1), "=&v"(q2), "=&v"(q3) : "v"(p) : "memory");
}
// Plain stores (no cache bits): write through into the XCD L2 and REST there
// — the level the sc0 polls read. (volatile would set sc0+sc1 and push past
// L2 — that was R5's hang.)
__device__ __forceinline__ void store_u64_plain(uint64_t* p, uint64_t v) {
    asm volatile("global_store_dwordx2 %0, %1, off" :: "v"(p), "v"(v) : "memory");
}
__device__ __forceinline__ void store_i32_plain(int* p, int v) {
    asm volatile("global_store_dword %0, %1, off" :: "v"(p), "v"(v) : "memory");
}

// ---------------------------------------------------------------------------
// Kernel 1: x [B][D][T] f32 -> xt in MFMA-A-fragment order (bf16 pairs, u32)
// ---------------------------------------------------------------------------
__global__ void xt_kernel(const float* __restrict__ x, uint32_t* __restrict__ xtf) {
    __shared__ unsigned short tile[16][128][17];   // [b_l][d][tl]
    const int bc = blockIdx.x >> 5;
    const int t0 = (blockIdx.x & 31) << 4;
    const int tid = threadIdx.x;

#pragma unroll
    for (int i = 0; i < 8; ++i) {
        int idx = i * 256 + tid;
        int b_l = idx >> 7, d = idx & 127;
        const float* src = x + ((size_t)(bc * 16 + b_l) * D_ + d) * T_ + t0;
        float4 f0 = *(const float4*)(src);
        float4 f1 = *(const float4*)(src + 4);
        float4 f2 = *(const float4*)(src + 8);
        float4 f3 = *(const float4*)(src + 12);
        unsigned short* dst = &tile[b_l][d][0];
        dst[0]=f2bf(f0.x); dst[1]=f2bf(f0.y); dst[2]=f2bf(f0.z); dst[3]=f2bf(f0.w);
        dst[4]=f2bf(f1.x); dst[5]=f2bf(f1.y); dst[6]=f2bf(f1.z); dst[7]=f2bf(f1.w);
        dst[8]=f2bf(f2.x); dst[9]=f2bf(f2.y); dst[10]=f2bf(f2.z); dst[11]=f2bf(f2.w);
        dst[12]=f2bf(f3.x); dst[13]=f2bf(f3.y); dst[14]=f2bf(f3.z); dst[15]=f2bf(f3.w);
    }
    __syncthreads();

    const int tl = tid >> 4;
    const int kk = (tid >> 2) & 3;
    const int lq = tid & 3;             // quad
    uint32_t vals[64];
#pragma unroll
    for (int q = 0; q < 64; ++q) {
        int brow = q >> 2;
        int e = q & 3;
        int d = kk * 32 + lq * 8 + e * 2;
        uint32_t lo = tile[brow][d][tl];
        uint32_t hi = tile[brow][d + 1][tl];
        vals[q] = lo | (hi << 16);
    }
    size_t S = ((((size_t)(t0 + tl) * 16 + bc) * 4 + kk) * 64 + (size_t)lq * 16) * 4;
#pragma unroll
    for (int q = 0; q < 16; ++q)
        *(uint4*)(xtf + S + q * 4) = *(uint4*)&vals[q * 4];
}

// ---------------------------------------------------------------------------
// Kernel 2: persistent LSTM recurrence + fused output projection.
// 256 blocks = 16 bc x 16 hc, 256 threads (4 waves, wave = gate).
// Fast path (same-XCD exchange through the shared L2) is enabled ONLY if:
//  (a) all 16 group members report the same XCC_ID, AND
//  (b) a bounded 4-round ping-pong through the exact fast mechanism
//      (plain store -> sc0 load) succeeds.
// Verdicts are AND-reduced group-wide over the agent-scope (MALL) channel.
// All fast-path spins share a budget -> kernel ALWAYS terminates.
// Fallback: R4's proven agent-scope protocol.
// ---------------------------------------------------------------------------
__global__ void __launch_bounds__(256) lstm_kernel(
    const float* __restrict__ Wgx, const float* __restrict__ Wix,
    const float* __restrict__ Wfx, const float* __restrict__ Wox,
    const float* __restrict__ Wgh, const float* __restrict__ Wih,
    const float* __restrict__ Wfh, const float* __restrict__ Woh,
    const float* __restrict__ bg,  const float* __restrict__ bi,
    const float* __restrict__ bf2, const float* __restrict__ bo,
    const uint32_t* __restrict__ xtf,
    uint64_t* __restrict__ hbuf,
    int* __restrict__ flags,
    int* __restrict__ xccbuf,
    int* __restrict__ vbuf,
    int* __restrict__ pbuf,
    const float* __restrict__ Wph, const float* __restrict__ bp,
    float* __restrict__ out)
{
    __shared__ __align__(16) unsigned short Wh_s[4][16][264];
    __shared__ __align__(16) unsigned short Wx_s[4][16][136];
    __shared__ __align__(16) unsigned short h_s[2][16][264];   // parity-buffered
    __shared__ float pre_s[4][16][17];
    __shared__ float bias_s[4][16];
    __shared__ int fast_s;

    const int tid  = threadIdx.x;
    const int bc   = blockIdx.x & 15;
    const int hc   = blockIdx.x >> 4;
    const int wave = tid >> 6;
    const int lane = tid & 63;
    const int mrow = lane & 15;
    const int quad = lane >> 4;

    // ---- W/bias staging into LDS (overlaps the probe phases below) ----
    const float* Wh[4] = {Wgh, Wih, Wfh, Woh};
    const float* Wx[4] = {Wgx, Wix, Wfx, Wox};
    const float* bias[4] = {bg, bi, bf2, bo};
#pragma unroll
    for (int g = 0; g < 4; ++g) {
        for (int it = 0; it < 16; ++it) {
            int idx = it * 256 + tid;
            int k = idx >> 4, c = idx & 15;
            Wh_s[g][c][k] = f2bf(Wh[g][(size_t)k * H_ + hc * 16 + c]);
        }
        for (int it = 0; it < 8; ++it) {
            int idx = it * 256 + tid;
            int k = idx >> 4, c = idx & 15;
            Wx_s[g][c][k] = f2bf(Wx[g][(size_t)k * H_ + hc * 16 + c]);
        }
    }
    if (tid < 64) bias_s[tid >> 4][tid & 15] = bias[tid >> 4][hc * 16 + (tid & 15)];

    // ---- Phase 0: XCC_ID publish & compare (agent scope, proven pattern) --
    // getreg imm = (size-1)<<11 | offset<<6 | id = 31<<11 | 0 | 20 = 63508.
    int xcc = __builtin_amdgcn_s_getreg(63508) & 0xF;
    if (tid == 0) {
        fast_s = 1;
        __hip_atomic_store(&xccbuf[blockIdx.x], 0x5A5A0000 | xcc,
                           __ATOMIC_RELAXED, __HIP_MEMORY_SCOPE_AGENT);
    }
    __syncthreads();
    if (tid < 16) {
        int peer = tid * 16 + bc;
        int v;
        do {
            v = __hip_atomic_load(&xccbuf[peer], __ATOMIC_RELAXED,
                                  __HIP_MEMORY_SCOPE_AGENT);
        } while ((v & 0xFFFF0000) != 0x5A5A0000);
        if ((v & 0xF) != xcc) atomicAnd(&fast_s, 0);
    }
    __syncthreads();
    const int v0 = fast_s;                     // group-uniform

    // ---- Phase 1: bounded ping-pong through the FAST mechanism ----
    int v1 = 1;
    int budget = 200000;
    if (v0) {
        for (int r = 0; r < 4; ++r) {
            __syncthreads();
            if (tid == 0)
                store_i32_plain(&pbuf[((bc * 16 + hc) * 4 + r) * 16], 0x3C000000 | r);
            if (tid < 16 && tid != hc) {
                const int* pp = &pbuf[((bc * 16 + tid) * 4 + r) * 16];
                int seen;
                do { seen = load_i32_sc0(pp); }
                while (seen != (0x3C000000 | r) && --budget > 0);
                if (seen != (0x3C000000 | r)) v1 = 0;
            }
        }
    }
    __syncthreads();
    if (tid < 16 && !v1) atomicAnd(&fast_s, 0);
    __syncthreads();

    // ---- Phase 2: group-wide verdict consensus over agent scope ----
    if (tid == 0)
        __hip_atomic_store(&vbuf[blockIdx.x], 0xC3C30000 | (fast_s & 1),
                           __ATOMIC_RELAXED, __HIP_MEMORY_SCOPE_AGENT);
    if (tid < 16) {
        int peer = tid * 16 + bc;
        int v;
        do {
            v = __hip_atomic_load(&vbuf[peer], __ATOMIC_RELAXED,
                                  __HIP_MEMORY_SCOPE_AGENT);
        } while (((unsigned)v & 0xFFFF0000u) != 0xC3C30000u);
        if (!(v & 1)) atomicAnd(&fast_s, 0);
    }
    __syncthreads();
    const bool fast = (fast_s != 0);           // group-uniform by construction

    const int b_l = tid >> 4;       // batch row within chunk
    const int u_l = tid & 15;       // unit within slice
    const int p_poll = b_l;         // producer this thread polls
    const int g_poll = u_l;         // row within producer's region
    const bool do_poll = (p_poll != hc);

    float c_st = 0.0f, h_st = 0.0f;
    int sbudget = 400000;           // fast-path spin budget (whole kernel)

    uint4 xv[4];
#pragma unroll
    for (int kk = 0; kk < 4; ++kk)
        xv[kk] = *(const uint4*)(xtf + ((((size_t)0 * 16 + bc) * 4 + kk) * 64 + lane) * 4);

    for (int t = 0; t < T_; ++t) {
        // ---- x-projection MFMAs (register A-frags) ----
        f32x4 accx = {0.f, 0.f, 0.f, 0.f};
#pragma unroll
        for (int kk = 0; kk < 4; ++kk) {
            s16x8 a  = as_frag(xv[kk]);
            s16x8 bb = *(const s16x8*)&Wx_s[wave][mrow][kk * 32 + quad * 8];
            accx = __builtin_amdgcn_mfma_f32_16x16x32_bf16(a, bb, accx, 0, 0, 0);
        }

        // ---- detect + fetch h(t-1) ----
        if (t > 0 && do_poll) {
            const int* fp = &flags[bc * 16 + p_poll];
            const uint64_t* L = hbuf +
                ((((size_t)((t - 1) & 1) * 16 + bc) * 16 + p_poll) * 16 + g_poll) * 8;
            const uint32_t want = (uint32_t)(t - 1);
            if (fast) {
                while (sbudget > 0 && load_i32_sc0(fp) < t) { --sbudget; }
                u32x4 q0, q1, q2, q3;
                while (true) {
                    load_64B_sc0(L, q0, q1, q2, q3);
                    bool ok = (q0[1] == want) & (q0[3] == want) &
                              (q1[1] == want) & (q1[3] == want) &
                              (q2[1] == want) & (q2[3] == want) &
                              (q3[1] == want) & (q3[3] == want);
                    if (ok || --sbudget <= 0) break;
                }
                u32x4 d0 = {q0[0], q0[2], q1[0], q1[2]};
                u32x4 d1 = {q2[0], q2[2], q3[0], q3[2]};
                *(u32x4*)&h_s[t & 1][g_poll][p_poll * 16]     = d0;
                *(u32x4*)&h_s[t & 1][g_poll][p_poll * 16 + 8] = d1;
            } else {
                while (__hip_atomic_load(fp, __ATOMIC_RELAXED,
                                         __HIP_MEMORY_SCOPE_AGENT) < t) {
                    __builtin_amdgcn_s_sleep(2);
                }
                uint64_t hv[8];
                while (true) {
#pragma unroll
                    for (int i = 0; i < 8; ++i)
                        hv[i] = __hip_atomic_load(&L[i], __ATOMIC_RELAXED,
                                                  __HIP_MEMORY_SCOPE_AGENT);
                    bool ok = true;
#pragma unroll
                    for (int i = 0; i < 8; ++i)
                        ok &= ((uint32_t)(hv[i] >> 32) == want);
                    if (ok) break;
                    __builtin_amdgcn_s_sleep(1);
                }
                uint32_t w[8];
#pragma unroll
                for (int i = 0; i < 8; ++i) w[i] = (uint32_t)hv[i];
                *(uint4*)&h_s[t & 1][g_poll][p_poll * 16]     = *(uint4*)&w[0];
                *(uint4*)&h_s[t & 1][g_poll][p_poll * 16 + 8] = *(uint4*)&w[4];
            }
        }
        bar_lds();   // B1: h_s[t&1] staged

        // ---- h-projection MFMAs (2 independent chains) ----
        f32x4 acc0 = {0.f, 0.f, 0.f, 0.f};
        f32x4 acc1 = {0.f, 0.f, 0.f, 0.f};
        if (t > 0) {
#pragma unroll
            for (int j = 0; j < 4; ++j) {
                s16x8 a  = *(const s16x8*)&h_s[t & 1][mrow][(2 * j) * 32 + quad * 8];
                s16x8 bb = *(const s16x8*)&Wh_s[wave][mrow][(2 * j) * 32 + quad * 8];
                acc0 = __builtin_amdgcn_mfma_f32_16x16x32_bf16(a, bb, acc0, 0, 0, 0);
                s16x8 a2  = *(const s16x8*)&h_s[t & 1][mrow][(2 * j + 1) * 32 + quad * 8];
                s16x8 bb2 = *(const s16x8*)&Wh_s[wave][mrow][(2 * j + 1) * 32 + quad * 8];
                acc1 = __builtin_amdgcn_mfma_f32_16x16x32_bf16(a2, bb2, acc1, 0, 0, 0);
            }
        }

#pragma unroll
        for (int r = 0; r < 4; ++r)
            pre_s[wave][quad * 4 + r][mrow] = accx[r] + acc0[r] + acc1[r];
        bar_lds();   // B2: pre-activations ready

        float pg = pre_s[0][b_l][u_l] + bias_s[0][u_l];
        float pi = pre_s[1][b_l][u_l] + bias_s[1][u_l];
        float pf = pre_s[2][b_l][u_l] + bias_s[2][u_l];
        float po = pre_s[3][b_l][u_l] + bias_s[3][u_l];
        float gg = 2.0f * sigm(2.0f * pg) - 1.0f;   // tanh
        float ii = sigm(pi), ff = sigm(pf), oo = sigm(po);
        c_st = gg * ii + c_st * ff;
        float th = 2.0f * sigm(2.0f * c_st) - 1.0f; // tanh(c)
        h_st = th * oo;

        uint32_t hb = f2bf(h_st);

        // local staging of own slice for next step
        h_s[(t + 1) & 1][b_l][hc * 16 + u_l] = (unsigned short)hb;

        // prefetch x fragments for t+1
        if (t + 1 < T_) {
#pragma unroll
            for (int kk = 0; kk < 4; ++kk)
                xv[kk] = *(const uint4*)(xtf +
                    ((((size_t)(t + 1) * 16 + bc) * 4 + kk) * 64 + lane) * 4);
        }

        // publish tagged data words, then flag (tags protect ordering)
        uint32_t p32 = hb | ((uint32_t)__shfl_down((int)hb, 1, 64) << 16);
        if ((u_l & 1) == 0) {
            uint64_t val = (uint64_t)p32 | ((uint64_t)(uint32_t)t << 32);
            uint64_t* dst = hbuf +
                ((((size_t)(t & 1) * 16 + bc) * 16 + hc) * 16 + b_l) * 8 + (u_l >> 1);
            if (fast) store_u64_plain(dst, val);        // rests in shared XCD L2
            else __hip_atomic_store(dst, val, __ATOMIC_RELAXED,
                                    __HIP_MEMORY_SCOPE_AGENT);
        }
        if (tid == 0) {
            if (fast) store_i32_plain(&flags[bc * 16 + hc], t + 1);
            else __hip_atomic_store(&flags[bc * 16 + hc], t + 1, __ATOMIC_RELAXED,
                                    __HIP_MEMORY_SCOPE_AGENT);
        }
    }

    // fused output projection
    {
        const int urow = hc * 16 + u_l;
        float wrow[C_];
#pragma unroll
        for (int c = 0; c < C_; ++c) wrow[c] = Wph[(size_t)urow * C_ + c];
#pragma unroll
        for (int c = 0; c < C_; ++c) {
            float v = h_st * wrow[c];
            v += __shfl_xor(v, 1, 64);
            v += __shfl_xor(v, 2, 64);
            v += __shfl_xor(v, 4, 64);
            v += __shfl_xor(v, 8, 64);
            if (u_l == 0) {
                if (hc == 0) v += bp[c];
                atomicAdd(&out[(size_t)(bc * 16 + b_l) * C_ + c], v);
            }
        }
    }
}

// ---------------------------------------------------------------------------
extern "C" void kernel_launch(void* const* d_in, const int* in_sizes, int n_in,
                              void* d_out, int out_size, void* d_ws, size_t ws_size,
                              hipStream_t stream) {
    const float* x   = (const float*)d_in[0];
    const float* Wgx = (const float*)d_in[1];
    const float* Wix = (const float*)d_in[2];
    const float* Wfx = (const float*)d_in[3];
    const float* Wox = (const float*)d_in[4];
    const float* Wgh = (const float*)d_in[5];
    const float* Wih = (const float*)d_in[6];
    const float* Wfh = (const float*)d_in[7];
    const float* Woh = (const float*)d_in[8];
    const float* bg  = (const float*)d_in[9];
    const float* bi  = (const float*)d_in[10];
    const float* bf2 = (const float*)d_in[11];
    const float* bo  = (const float*)d_in[12];
    const float* Wph = (const float*)d_in[13];
    const float* bp  = (const float*)d_in[14];

    char* ws = (char*)d_ws;
    // Poison 0xAA: flags negative -> always < t; xccbuf/vbuf/pbuf never match
    // their magics; hbuf tags never match a step tag. No memsets needed.
    int*      flags  = (int*)ws;                          // 1 KiB
    int*      xccbuf = (int*)(ws + 1024);                 // 1 KiB
    int*      vbuf   = (int*)(ws + 2048);                 // 1 KiB
    int*      pbuf   = (int*)(ws + 3072);                 // 64 KiB
    uint64_t* hbuf   = (uint64_t*)(ws + 3072 + 65536);    // 512 KiB
    uint32_t* xtf    = (uint32_t*)(ws + 3072 + 65536 + 2 * 16 * 16 * 16 * 8 * 8);

    hipMemsetAsync(d_out, 0, B_ * C_ * sizeof(float), stream);

    xt_kernel<<<16 * 32, 256, 0, stream>>>(x, xtf);

    lstm_kernel<<<256, 256, 0, stream>>>(Wgx, Wix, Wfx, Wox, Wgh, Wih, Wfh, Woh,
                                         bg, bi, bf2, bo, xtf, hbuf, flags,
                                         xccbuf, vbuf, pbuf,
                                         Wph, bp, (float*)d_out);
}

// Round 8
// 1912.508 us; speedup vs baseline: 23.6437x; 23.6437x over previous
//
#include <hip/hip_runtime.h>
#include <hip/hip_bf16.h>
#include <cstdint>

#define B_ 256
#define D_ 128
#define T_ 512
#define H_ 256
#define C_ 10

using f32x4 = __attribute__((ext_vector_type(4))) float;
using s16x8 = __attribute__((ext_vector_type(8))) short;

__device__ __forceinline__ unsigned short f2bf(float f) {
    union { float f; uint32_t u; } a; a.f = f;
    uint32_t u = a.u;
    uint32_t r = (u + 0x7fffu + ((u >> 16) & 1u)) >> 16;   // RNE
    return (unsigned short)r;
}

__device__ __forceinline__ float sigm(float v) { return 1.0f / (1.0f + __expf(-v)); }

__device__ __forceinline__ s16x8 as_frag(uint4 v) {
    union { uint4 u; s16x8 s; } c; c.u = v; return c.s;
}

// lgkm-only barrier: orders LDS without draining in-flight global ops.
__device__ __forceinline__ void bar_lds() {
    asm volatile("s_waitcnt lgkmcnt(0)\n\ts_barrier" ::: "memory");
}

// ---------------------------------------------------------------------------
// Kernel 1: x [B][D][T] f32 -> xt in MFMA-A-fragment order (bf16 pairs, u32):
//   idx32(t,bc,kk,lane,e) = (((t*16+bc)*4+kk)*64 + lane)*4 + e
// ---------------------------------------------------------------------------
__global__ void xt_kernel(const float* __restrict__ x, uint32_t* __restrict__ xtf) {
    __shared__ unsigned short tile[16][128][17];   // [b_l][d][tl]
    const int bc = blockIdx.x >> 5;
    const int t0 = (blockIdx.x & 31) << 4;
    const int tid = threadIdx.x;

#pragma unroll
    for (int i = 0; i < 8; ++i) {
        int idx = i * 256 + tid;
        int b_l = idx >> 7, d = idx & 127;
        const float* src = x + ((size_t)(bc * 16 + b_l) * D_ + d) * T_ + t0;
        float4 f0 = *(const float4*)(src);
        float4 f1 = *(const float4*)(src + 4);
        float4 f2 = *(const float4*)(src + 8);
        float4 f3 = *(const float4*)(src + 12);
        unsigned short* dst = &tile[b_l][d][0];
        dst[0]=f2bf(f0.x); dst[1]=f2bf(f0.y); dst[2]=f2bf(f0.z); dst[3]=f2bf(f0.w);
        dst[4]=f2bf(f1.x); dst[5]=f2bf(f1.y); dst[6]=f2bf(f1.z); dst[7]=f2bf(f1.w);
        dst[8]=f2bf(f2.x); dst[9]=f2bf(f2.y); dst[10]=f2bf(f2.z); dst[11]=f2bf(f2.w);
        dst[12]=f2bf(f3.x); dst[13]=f2bf(f3.y); dst[14]=f2bf(f3.z); dst[15]=f2bf(f3.w);
    }
    __syncthreads();

    const int tl = tid >> 4;
    const int kk = (tid >> 2) & 3;
    const int lq = tid & 3;             // quad
    uint32_t vals[64];
#pragma unroll
    for (int q = 0; q < 64; ++q) {
        int brow = q >> 2;
        int e = q & 3;
        int d = kk * 32 + lq * 8 + e * 2;
        uint32_t lo = tile[brow][d][tl];
        uint32_t hi = tile[brow][d + 1][tl];
        vals[q] = lo | (hi << 16);
    }
    size_t S = ((((size_t)(t0 + tl) * 16 + bc) * 4 + kk) * 64 + (size_t)lq * 16) * 4;
#pragma unroll
    for (int q = 0; q < 16; ++q)
        *(uint4*)(xtf + S + q * 4) = *(uint4*)&vals[q * 4];
}

// ---------------------------------------------------------------------------
// Kernel 2: persistent LSTM recurrence + fused output projection.
// 256 blocks = 16 bc x 16 hc, 256 threads (4 waves, wave = gate).
// Exchange protocol (all agent-scope RELAXED, MALL-resident — the only
// proven-correct channel; no drains, no acquire/release):
//   producer: 128 tagged u64 ([t | 2 bf16]) then flag = t+1
//   consumer: speculative 64B fetch at loop top; 16 pollers (excl. own flag)
//             gate on flags; barrier; verify tags; cheap refetch if stale.
// Deadlock-free: retries wait only on already-issued stores. Overwrite-safe:
// P overwrites tag-t (end of P's t+2) only after all peers published t+1,
// which follows their completed fetch of tag-t.
// ---------------------------------------------------------------------------
__global__ void __launch_bounds__(256) lstm_kernel(
    const float* __restrict__ Wgx, const float* __restrict__ Wix,
    const float* __restrict__ Wfx, const float* __restrict__ Wox,
    const float* __restrict__ Wgh, const float* __restrict__ Wih,
    const float* __restrict__ Wfh, const float* __restrict__ Woh,
    const float* __restrict__ bg,  const float* __restrict__ bi,
    const float* __restrict__ bf2, const float* __restrict__ bo,
    const uint32_t* __restrict__ xtf,
    uint64_t* __restrict__ hbuf,
    int* __restrict__ flags,
    const float* __restrict__ Wph, const float* __restrict__ bp,
    float* __restrict__ out)
{
    __shared__ __align__(16) unsigned short Wh_s[4][16][264];
    __shared__ __align__(16) unsigned short Wx_s[4][16][136];
    __shared__ __align__(16) unsigned short h_s[2][16][264];   // parity-buffered
    __shared__ float pre_s[4][16][17];
    __shared__ float bias_s[4][16];

    const int tid  = threadIdx.x;
    const int bc   = blockIdx.x & 15;
    const int hc   = blockIdx.x >> 4;
    const int wave = tid >> 6;
    const int lane = tid & 63;
    const int mrow = lane & 15;
    const int quad = lane >> 4;

    const float* Wh[4] = {Wgh, Wih, Wfh, Woh};
    const float* Wx[4] = {Wgx, Wix, Wfx, Wox};
    const float* bias[4] = {bg, bi, bf2, bo};

#pragma unroll
    for (int g = 0; g < 4; ++g) {
        for (int it = 0; it < 16; ++it) {
            int idx = it * 256 + tid;
            int k = idx >> 4, c = idx & 15;
            Wh_s[g][c][k] = f2bf(Wh[g][(size_t)k * H_ + hc * 16 + c]);
        }
        for (int it = 0; it < 8; ++it) {
            int idx = it * 256 + tid;
            int k = idx >> 4, c = idx & 15;
            Wx_s[g][c][k] = f2bf(Wx[g][(size_t)k * H_ + hc * 16 + c]);
        }
    }
    if (tid < 64) bias_s[tid >> 4][tid & 15] = bias[tid >> 4][hc * 16 + (tid & 15)];
    __syncthreads();

    const int b_l = tid >> 4;       // batch row within chunk
    const int u_l = tid & 15;       // unit within slice
    const int p_poll = b_l;         // producer this thread fetches from
    const int g_poll = u_l;         // row within producer's region
    const bool do_fetch = (p_poll != hc);
    const bool is_poller = (tid < 16) && (tid != hc);   // own flag: skip (own
                                                        // data comes via LDS)

    float c_st = 0.0f, h_st = 0.0f;

    uint4 xv[4];
#pragma unroll
    for (int kk = 0; kk < 4; ++kk)
        xv[kk] = *(const uint4*)(xtf + ((((size_t)0 * 16 + bc) * 4 + kk) * 64 + lane) * 4);

    for (int t = 0; t < T_; ++t) {
        const uint64_t* L = hbuf +
            ((((size_t)((t - 1) & 1) * 16 + bc) * 16 + p_poll) * 16 + g_poll) * 8;
        const uint32_t want = (uint32_t)(t - 1);

        // ---- speculative 64B fetch of h(t-1) line (overlaps everything) ----
        uint64_t hv[8];
        if (t > 0 && do_fetch) {
#pragma unroll
            for (int i = 0; i < 8; ++i)
                hv[i] = __hip_atomic_load(&L[i], __ATOMIC_RELAXED,
                                          __HIP_MEMORY_SCOPE_AGENT);
        }

        // ---- x-projection MFMAs (register A-frags, no staging) ----
        f32x4 accx = {0.f, 0.f, 0.f, 0.f};
#pragma unroll
        for (int kk = 0; kk < 4; ++kk) {
            s16x8 a  = as_frag(xv[kk]);
            s16x8 bb = *(const s16x8*)&Wx_s[wave][mrow][kk * 32 + quad * 8];
            accx = __builtin_amdgcn_mfma_f32_16x16x32_bf16(a, bb, accx, 0, 0, 0);
        }

        // ---- flag gate: 16 pollers, then release the block ----
        if (t > 0 && is_poller) {
            const int* fp = &flags[bc * 16 + tid];
            int v = __hip_atomic_load(fp, __ATOMIC_RELAXED, __HIP_MEMORY_SCOPE_AGENT);
            while (v < t) {
                __builtin_amdgcn_s_sleep(1);
                v = __hip_atomic_load(fp, __ATOMIC_RELAXED, __HIP_MEMORY_SCOPE_AGENT);
            }
        }
        bar_lds();   // P: all producers have published step t-1

        // ---- verify speculative data; refetch if stale (rare) ----
        if (t > 0 && do_fetch) {
            while (true) {
                bool ok = true;
#pragma unroll
                for (int i = 0; i < 8; ++i)
                    ok &= ((uint32_t)(hv[i] >> 32) == want);
                if (ok) break;
#pragma unroll
                for (int i = 0; i < 8; ++i)
                    hv[i] = __hip_atomic_load(&L[i], __ATOMIC_RELAXED,
                                              __HIP_MEMORY_SCOPE_AGENT);
            }
            uint32_t w[8];
#pragma unroll
            for (int i = 0; i < 8; ++i) w[i] = (uint32_t)hv[i];
            *(uint4*)&h_s[t & 1][g_poll][p_poll * 16]     = *(uint4*)&w[0];
            *(uint4*)&h_s[t & 1][g_poll][p_poll * 16 + 8] = *(uint4*)&w[4];
        }
        bar_lds();   // B1: h_s[t&1] complete (incl. own slice from t-1 epilogue)

        // ---- h-projection MFMAs (2 independent chains) ----
        f32x4 acc0 = {0.f, 0.f, 0.f, 0.f};
        f32x4 acc1 = {0.f, 0.f, 0.f, 0.f};
        if (t > 0) {
#pragma unroll
            for (int j = 0; j < 4; ++j) {
                s16x8 a  = *(const s16x8*)&h_s[t & 1][mrow][(2 * j) * 32 + quad * 8];
                s16x8 bb = *(const s16x8*)&Wh_s[wave][mrow][(2 * j) * 32 + quad * 8];
                acc0 = __builtin_amdgcn_mfma_f32_16x16x32_bf16(a, bb, acc0, 0, 0, 0);
                s16x8 a2  = *(const s16x8*)&h_s[t & 1][mrow][(2 * j + 1) * 32 + quad * 8];
                s16x8 bb2 = *(const s16x8*)&Wh_s[wave][mrow][(2 * j + 1) * 32 + quad * 8];
                acc1 = __builtin_amdgcn_mfma_f32_16x16x32_bf16(a2, bb2, acc1, 0, 0, 0);
            }
        }

#pragma unroll
        for (int r = 0; r < 4; ++r)
            pre_s[wave][quad * 4 + r][mrow] = accx[r] + acc0[r] + acc1[r];
        bar_lds();   // B2: pre-activations ready

        float pg = pre_s[0][b_l][u_l] + bias_s[0][u_l];
        float pi = pre_s[1][b_l][u_l] + bias_s[1][u_l];
        float pf = pre_s[2][b_l][u_l] + bias_s[2][u_l];
        float po = pre_s[3][b_l][u_l] + bias_s[3][u_l];
        float gg = 2.0f * sigm(2.0f * pg) - 1.0f;   // tanh
        float ii = sigm(pi), ff = sigm(pf), oo = sigm(po);
        c_st = gg * ii + c_st * ff;
        float th = 2.0f * sigm(2.0f * c_st) - 1.0f; // tanh(c)
        h_st = th * oo;

        uint32_t hb = f2bf(h_st);

        // local staging of own slice for next step (no global round trip)
        h_s[(t + 1) & 1][b_l][hc * 16 + u_l] = (unsigned short)hb;

        // prefetch x fragments for t+1 (consumed at next loop top)
        if (t + 1 < T_) {
#pragma unroll
            for (int kk = 0; kk < 4; ++kk)
                xv[kk] = *(const uint4*)(xtf +
                    ((((size_t)(t + 1) * 16 + bc) * 4 + kk) * 64 + lane) * 4);
        }

        // publish tagged data, then flag — both relaxed, no drain
        uint32_t p32 = hb | ((uint32_t)__shfl_down((int)hb, 1, 64) << 16);
        if ((u_l & 1) == 0) {
            uint64_t val = (uint64_t)p32 | ((uint64_t)(uint32_t)t << 32);
            uint64_t* dst = hbuf +
                ((((size_t)(t & 1) * 16 + bc) * 16 + hc) * 16 + b_l) * 8 + (u_l >> 1);
            __hip_atomic_store(dst, val, __ATOMIC_RELAXED, __HIP_MEMORY_SCOPE_AGENT);
        }
        if (tid == 0)
            __hip_atomic_store(&flags[bc * 16 + hc], t + 1, __ATOMIC_RELAXED,
                               __HIP_MEMORY_SCOPE_AGENT);
    }

    // fused output projection
    {
        const int urow = hc * 16 + u_l;
        float wrow[C_];
#pragma unroll
        for (int c = 0; c < C_; ++c) wrow[c] = Wph[(size_t)urow * C_ + c];
#pragma unroll
        for (int c = 0; c < C_; ++c) {
            float v = h_st * wrow[c];
            v += __shfl_xor(v, 1, 64);
            v += __shfl_xor(v, 2, 64);
            v += __shfl_xor(v, 4, 64);
            v += __shfl_xor(v, 8, 64);
            if (u_l == 0) {
                if (hc == 0) v += bp[c];
                atomicAdd(&out[(size_t)(bc * 16 + b_l) * C_ + c], v);
            }
        }
    }
}

// ---------------------------------------------------------------------------
extern "C" void kernel_launch(void* const* d_in, const int* in_sizes, int n_in,
                              void* d_out, int out_size, void* d_ws, size_t ws_size,
                              hipStream_t stream) {
    const float* x   = (const float*)d_in[0];
    const float* Wgx = (const float*)d_in[1];
    const float* Wix = (const float*)d_in[2];
    const float* Wfx = (const float*)d_in[3];
    const float* Wox = (const float*)d_in[4];
    const float* Wgh = (const float*)d_in[5];
    const float* Wih = (const float*)d_in[6];
    const float* Wfh = (const float*)d_in[7];
    const float* Woh = (const float*)d_in[8];
    const float* bg  = (const float*)d_in[9];
    const float* bi  = (const float*)d_in[10];
    const float* bf2 = (const float*)d_in[11];
    const float* bo  = (const float*)d_in[12];
    const float* Wph = (const float*)d_in[13];
    const float* bp  = (const float*)d_in[14];

    char* ws = (char*)d_ws;
    // Poison 0xAA: flags negative int -> spin holds; hbuf tags never match a
    // real step tag. No memsets needed for the protocol state.
    int*      flags = (int*)ws;                           // 1 KiB
    uint64_t* hbuf  = (uint64_t*)(ws + 1024);             // 512 KiB
    uint32_t* xtf   = (uint32_t*)(ws + 1024 + 2 * 16 * 16 * 16 * 8 * 8);

    hipMemsetAsync(d_out, 0, B_ * C_ * sizeof(float), stream);

    xt_kernel<<<16 * 32, 256, 0, stream>>>(x, xtf);

    lstm_kernel<<<256, 256, 0, stream>>>(Wgx, Wix, Wfx, Wox, Wgh, Wih, Wfh, Woh,
                                         bg, bi, bf2, bo, xtf, hbuf, flags,
                                         Wph, bp, (float*)d_out);
}

// Round 9
// 1312.235 us; speedup vs baseline: 34.4593x; 1.4574x over previous
//
#include <hip/hip_runtime.h>
#include <hip/hip_bf16.h>
#include <cstdint>

#define B_ 256
#define D_ 128
#define T_ 512
#define H_ 256
#define C_ 10

using f32x4 = __attribute__((ext_vector_type(4))) float;
using s16x8 = __attribute__((ext_vector_type(8))) short;

__device__ __forceinline__ unsigned short f2bf(float f) {
    union { float f; uint32_t u; } a; a.f = f;
    uint32_t u = a.u;
    uint32_t r = (u + 0x7fffu + ((u >> 16) & 1u)) >> 16;   // RNE
    return (unsigned short)r;
}

__device__ __forceinline__ float sigm(float v) { return 1.0f / (1.0f + __expf(-v)); }

__device__ __forceinline__ s16x8 as_frag(uint4 v) {
    union { uint4 u; s16x8 s; } c; c.u = v; return c.s;
}

// lgkm-only barrier: orders LDS without draining in-flight global ops.
__device__ __forceinline__ void bar_lds() {
    asm volatile("s_waitcnt lgkmcnt(0)\n\ts_barrier" ::: "memory");
}

// ---------------------------------------------------------------------------
// Kernel 1: x [B][D][T] f32 -> xt in MFMA-A-fragment order (bf16 pairs, u32):
//   idx32(t,bc,kk,lane,e) = (((t*16+bc)*4+kk)*64 + lane)*4 + e
// ---------------------------------------------------------------------------
__global__ void xt_kernel(const float* __restrict__ x, uint32_t* __restrict__ xtf) {
    __shared__ unsigned short tile[16][128][17];   // [b_l][d][tl]
    const int bc = blockIdx.x >> 5;
    const int t0 = (blockIdx.x & 31) << 4;
    const int tid = threadIdx.x;

#pragma unroll
    for (int i = 0; i < 8; ++i) {
        int idx = i * 256 + tid;
        int b_l = idx >> 7, d = idx & 127;
        const float* src = x + ((size_t)(bc * 16 + b_l) * D_ + d) * T_ + t0;
        float4 f0 = *(const float4*)(src);
        float4 f1 = *(const float4*)(src + 4);
        float4 f2 = *(const float4*)(src + 8);
        float4 f3 = *(const float4*)(src + 12);
        unsigned short* dst = &tile[b_l][d][0];
        dst[0]=f2bf(f0.x); dst[1]=f2bf(f0.y); dst[2]=f2bf(f0.z); dst[3]=f2bf(f0.w);
        dst[4]=f2bf(f1.x); dst[5]=f2bf(f1.y); dst[6]=f2bf(f1.z); dst[7]=f2bf(f1.w);
        dst[8]=f2bf(f2.x); dst[9]=f2bf(f2.y); dst[10]=f2bf(f2.z); dst[11]=f2bf(f2.w);
        dst[12]=f2bf(f3.x); dst[13]=f2bf(f3.y); dst[14]=f2bf(f3.z); dst[15]=f2bf(f3.w);
    }
    __syncthreads();

    const int tl = tid >> 4;
    const int kk = (tid >> 2) & 3;
    const int lq = tid & 3;             // quad
    uint32_t vals[64];
#pragma unroll
    for (int q = 0; q < 64; ++q) {
        int brow = q >> 2;
        int e = q & 3;
        int d = kk * 32 + lq * 8 + e * 2;
        uint32_t lo = tile[brow][d][tl];
        uint32_t hi = tile[brow][d + 1][tl];
        vals[q] = lo | (hi << 16);
    }
    size_t S = ((((size_t)(t0 + tl) * 16 + bc) * 4 + kk) * 64 + (size_t)lq * 16) * 4;
#pragma unroll
    for (int q = 0; q < 16; ++q)
        *(uint4*)(xtf + S + q * 4) = *(uint4*)&vals[q * 4];
}

// ---------------------------------------------------------------------------
// Kernel 2: persistent LSTM recurrence + fused output projection.
// 256 blocks = 16 bc x 16 hc, 256 threads (4 waves, wave = gate).
// Exchange protocol — NO flags: each consumer thread polls ONE 64B line
// (its producer's 8 tagged u64 [t | 2 bf16], written by a single wave-store
// on the producer side) until all 8 tags == t-1. Detection IS data delivery:
// one MALL round trip. One poller per line -> no hot-line contention (R4),
// no scattered multi-line gating (R3), no flag->data serialization (R2/R8).
// All agent-scope RELAXED; no drains/acquire/release.
// Overwrite-safe: P overwrites tag-t (end of P's t+2) only after all peers
// published t+1, which follows their completed verified fetch of tag-t.
// ---------------------------------------------------------------------------
__global__ void __launch_bounds__(256) lstm_kernel(
    const float* __restrict__ Wgx, const float* __restrict__ Wix,
    const float* __restrict__ Wfx, const float* __restrict__ Wox,
    const float* __restrict__ Wgh, const float* __restrict__ Wih,
    const float* __restrict__ Wfh, const float* __restrict__ Woh,
    const float* __restrict__ bg,  const float* __restrict__ bi,
    const float* __restrict__ bf2, const float* __restrict__ bo,
    const uint32_t* __restrict__ xtf,
    uint64_t* __restrict__ hbuf,
    const float* __restrict__ Wph, const float* __restrict__ bp,
    float* __restrict__ out)
{
    __shared__ __align__(16) unsigned short Wh_s[4][16][264];
    __shared__ __align__(16) unsigned short Wx_s[4][16][136];
    __shared__ __align__(16) unsigned short h_s[2][16][264];   // parity-buffered
    __shared__ float pre_s[4][16][17];
    __shared__ float bias_s[4][16];

    const int tid  = threadIdx.x;
    const int bc   = blockIdx.x & 15;
    const int hc   = blockIdx.x >> 4;
    const int wave = tid >> 6;
    const int lane = tid & 63;
    const int mrow = lane & 15;
    const int quad = lane >> 4;

    const float* Wh[4] = {Wgh, Wih, Wfh, Woh};
    const float* Wx[4] = {Wgx, Wix, Wfx, Wox};
    const float* bias[4] = {bg, bi, bf2, bo};

#pragma unroll
    for (int g = 0; g < 4; ++g) {
        for (int it = 0; it < 16; ++it) {
            int idx = it * 256 + tid;
            int k = idx >> 4, c = idx & 15;
            Wh_s[g][c][k] = f2bf(Wh[g][(size_t)k * H_ + hc * 16 + c]);
        }
        for (int it = 0; it < 8; ++it) {
            int idx = it * 256 + tid;
            int k = idx >> 4, c = idx & 15;
            Wx_s[g][c][k] = f2bf(Wx[g][(size_t)k * H_ + hc * 16 + c]);
        }
    }
    if (tid < 64) bias_s[tid >> 4][tid & 15] = bias[tid >> 4][hc * 16 + (tid & 15)];
    __syncthreads();

    const int b_l = tid >> 4;       // batch row within chunk
    const int u_l = tid & 15;       // unit within slice
    const int p_poll = b_l;         // producer this thread fetches from
    const int g_poll = u_l;         // row within producer's region
    const bool do_fetch = (p_poll != hc);   // own slice arrives via LDS

    float c_st = 0.0f, h_st = 0.0f;

    uint4 xv[4];
#pragma unroll
    for (int kk = 0; kk < 4; ++kk)
        xv[kk] = *(const uint4*)(xtf + ((((size_t)0 * 16 + bc) * 4 + kk) * 64 + lane) * 4);

    for (int t = 0; t < T_; ++t) {
        // ---- x-projection MFMAs (register A-frags; off the critical path) --
        f32x4 accx = {0.f, 0.f, 0.f, 0.f};
#pragma unroll
        for (int kk = 0; kk < 4; ++kk) {
            s16x8 a  = as_frag(xv[kk]);
            s16x8 bb = *(const s16x8*)&Wx_s[wave][mrow][kk * 32 + quad * 8];
            accx = __builtin_amdgcn_mfma_f32_16x16x32_bf16(a, bb, accx, 0, 0, 0);
        }

        // ---- poll own 64B line: detection == data delivery (one RTT) ----
        if (t > 0 && do_fetch) {
            const uint64_t* L = hbuf +
                ((((size_t)((t - 1) & 1) * 16 + bc) * 16 + p_poll) * 16 + g_poll) * 8;
            const uint32_t want = (uint32_t)(t - 1);
            uint64_t hv[8];
            while (true) {
#pragma unroll
                for (int i = 0; i < 8; ++i)
                    hv[i] = __hip_atomic_load(&L[i], __ATOMIC_RELAXED,
                                              __HIP_MEMORY_SCOPE_AGENT);
                bool ok = true;
#pragma unroll
                for (int i = 0; i < 8; ++i)
                    ok &= ((uint32_t)(hv[i] >> 32) == want);
                if (ok) break;
            }
            uint32_t w[8];
#pragma unroll
            for (int i = 0; i < 8; ++i) w[i] = (uint32_t)hv[i];
            *(uint4*)&h_s[t & 1][g_poll][p_poll * 16]     = *(uint4*)&w[0];
            *(uint4*)&h_s[t & 1][g_poll][p_poll * 16 + 8] = *(uint4*)&w[4];
        }
        bar_lds();   // B1: h_s[t&1] complete (incl. own slice from t-1 epilogue)

        // ---- h-projection MFMAs (2 independent chains) ----
        f32x4 acc0 = {0.f, 0.f, 0.f, 0.f};
        f32x4 acc1 = {0.f, 0.f, 0.f, 0.f};
        if (t > 0) {
#pragma unroll
            for (int j = 0; j < 4; ++j) {
                s16x8 a  = *(const s16x8*)&h_s[t & 1][mrow][(2 * j) * 32 + quad * 8];
                s16x8 bb = *(const s16x8*)&Wh_s[wave][mrow][(2 * j) * 32 + quad * 8];
                acc0 = __builtin_amdgcn_mfma_f32_16x16x32_bf16(a, bb, acc0, 0, 0, 0);
                s16x8 a2  = *(const s16x8*)&h_s[t & 1][mrow][(2 * j + 1) * 32 + quad * 8];
                s16x8 bb2 = *(const s16x8*)&Wh_s[wave][mrow][(2 * j + 1) * 32 + quad * 8];
                acc1 = __builtin_amdgcn_mfma_f32_16x16x32_bf16(a2, bb2, acc1, 0, 0, 0);
            }
        }

#pragma unroll
        for (int r = 0; r < 4; ++r)
            pre_s[wave][quad * 4 + r][mrow] = accx[r] + acc0[r] + acc1[r];
        bar_lds();   // B2: pre-activations ready

        float pg = pre_s[0][b_l][u_l] + bias_s[0][u_l];
        float pi = pre_s[1][b_l][u_l] + bias_s[1][u_l];
        float pf = pre_s[2][b_l][u_l] + bias_s[2][u_l];
        float po = pre_s[3][b_l][u_l] + bias_s[3][u_l];
        float gg = 2.0f * sigm(2.0f * pg) - 1.0f;   // tanh
        float ii = sigm(pi), ff = sigm(pf), oo = sigm(po);
        c_st = gg * ii + c_st * ff;
        float th = 2.0f * sigm(2.0f * c_st) - 1.0f; // tanh(c)
        h_st = th * oo;

        uint32_t hb = f2bf(h_st);

        // local staging of own slice for next step (no global round trip)
        h_s[(t + 1) & 1][b_l][hc * 16 + u_l] = (unsigned short)hb;

        // prefetch x fragments for t+1 (consumed at next loop top)
        if (t + 1 < T_) {
#pragma unroll
            for (int kk = 0; kk < 4; ++kk)
                xv[kk] = *(const uint4*)(xtf +
                    ((((size_t)(t + 1) * 16 + bc) * 4 + kk) * 64 + lane) * 4);
        }

        // publish tagged data — one wave-store covers each 64B line; relaxed
        uint32_t p32 = hb | ((uint32_t)__shfl_down((int)hb, 1, 64) << 16);
        if ((u_l & 1) == 0) {
            uint64_t val = (uint64_t)p32 | ((uint64_t)(uint32_t)t << 32);
            uint64_t* dst = hbuf +
                ((((size_t)(t & 1) * 16 + bc) * 16 + hc) * 16 + b_l) * 8 + (u_l >> 1);
            __hip_atomic_store(dst, val, __ATOMIC_RELAXED, __HIP_MEMORY_SCOPE_AGENT);
        }
    }

    // fused output projection
    {
        const int urow = hc * 16 + u_l;
        float wrow[C_];
#pragma unroll
        for (int c = 0; c < C_; ++c) wrow[c] = Wph[(size_t)urow * C_ + c];
#pragma unroll
        for (int c = 0; c < C_; ++c) {
            float v = h_st * wrow[c];
            v += __shfl_xor(v, 1, 64);
            v += __shfl_xor(v, 2, 64);
            v += __shfl_xor(v, 4, 64);
            v += __shfl_xor(v, 8, 64);
            if (u_l == 0) {
                if (hc == 0) v += bp[c];
                atomicAdd(&out[(size_t)(bc * 16 + b_l) * C_ + c], v);
            }
        }
    }
}

// ---------------------------------------------------------------------------
extern "C" void kernel_launch(void* const* d_in, const int* in_sizes, int n_in,
                              void* d_out, int out_size, void* d_ws, size_t ws_size,
                              hipStream_t stream) {
    const float* x   = (const float*)d_in[0];
    const float* Wgx = (const float*)d_in[1];
    const float* Wix = (const float*)d_in[2];
    const float* Wfx = (const float*)d_in[3];
    const float* Wox = (const float*)d_in[4];
    const float* Wgh = (const float*)d_in[5];
    const float* Wih = (const float*)d_in[6];
    const float* Wfh = (const float*)d_in[7];
    const float* Woh = (const float*)d_in[8];
    const float* bg  = (const float*)d_in[9];
    const float* bi  = (const float*)d_in[10];
    const float* bf2 = (const float*)d_in[11];
    const float* bo  = (const float*)d_in[12];
    const float* Wph = (const float*)d_in[13];
    const float* bp  = (const float*)d_in[14];

    char* ws = (char*)d_ws;
    // Poison 0xAA: hbuf tags never match a real step tag -> polls hold until
    // genuine data arrives. No memsets needed for protocol state.
    uint64_t* hbuf = (uint64_t*)ws;                       // 512 KiB
    uint32_t* xtf  = (uint32_t*)(ws + 2 * 16 * 16 * 16 * 8 * 8);

    hipMemsetAsync(d_out, 0, B_ * C_ * sizeof(float), stream);

    xt_kernel<<<16 * 32, 256, 0, stream>>>(x, xtf);

    lstm_kernel<<<256, 256, 0, stream>>>(Wgx, Wix, Wfx, Wox, Wgh, Wih, Wfh, Woh,
                                         bg, bi, bf2, bo, xtf, hbuf,
                                         Wph, bp, (float*)d_out);
}